// Round 6
// baseline (179.889 us; speedup 1.0000x reference)
//
#include <hip/hip_runtime.h>
#include <math.h>
#include <stdint.h>

#define NPTS 35937        // 33^3
#define HID 256
#define TPB 256

typedef __attribute__((ext_vector_type(8))) short short8;
typedef __attribute__((ext_vector_type(4))) float f32x4;

// ---------- helpers ----------
__device__ __forceinline__ float fast_tanh(float x) {
    float e = __expf(2.0f * x);
    return 1.0f - __fdividef(2.0f, e + 1.0f);
}

__device__ __forceinline__ short f2bf(float f) {   // RNE float->bf16
    union { float f; unsigned u; } v; v.f = f;
    unsigned r = (v.u + 0x7fffu + ((v.u >> 16) & 1u)) >> 16;
    return (short)r;
}

// order-preserving float<->uint transforms (for atomic min/max on floats)
__device__ __forceinline__ unsigned f2ord(float f) {
    unsigned u = __float_as_uint(f);
    return (u & 0x80000000u) ? ~u : (u | 0x80000000u);
}
__device__ __forceinline__ float ord2f(unsigned o) {
    unsigned u = (o & 0x80000000u) ? (o & 0x7fffffffu) : ~o;
    return __uint_as_float(u);
}

// ---------- workspace layout (bytes) ----------
// P      [0, 417792)            bf16 packed weights
// lut4   [417792, 992784)       fp32x4 LUT (35937 * 16 B)
// rng    [992784, 992792)       {ordered-min, ordered-max} of LUT values
// pcode  [1048576, 1192324)     packed 11/11/10 codes, one u32 per grid point
#define W1P_OFF 8192
#define W2P_OFF 73728
#define W3P_OFF 139264
#define W4P_OFF 204800
#define LUT_BYTE_OFF 417792
#define RNG_BYTE_OFF 992784
#define PCODE_BYTE_OFF 1048576

__global__ __launch_bounds__(256) void pack_weights_kernel(
    const float* __restrict__ W0, const float* __restrict__ W1,
    const float* __restrict__ W2, const float* __restrict__ W3,
    const float* __restrict__ W4, short* __restrict__ P,
    unsigned* __restrict__ rng)
{
    int id = blockIdx.x * 256 + threadIdx.x;
    if (id == 0) { rng[0] = 0xFFFFFFFFu; rng[1] = 0u; }   // init min/max slots each call
    if (id >= 26112) return;
    const float* W; int f, NT, KREAL, NROW; long pbase;
    if (id < 1024)       { W = W0; f = id;         NT = 16; KREAL = 11;  NROW = 256; pbase = 0; }
    else if (id < 9216)  { W = W1; f = id - 1024;  NT = 16; KREAL = 256; NROW = 256; pbase = W1P_OFF; }
    else if (id < 17408) { W = W2; f = id - 9216;  NT = 16; KREAL = 256; NROW = 256; pbase = W2P_OFF; }
    else if (id < 25600) { W = W3; f = id - 17408; NT = 16; KREAL = 256; NROW = 256; pbase = W3P_OFF; }
    else                 { W = W4; f = id - 25600; NT = 1;  KREAL = 256; NROW = 3;   pbase = W4P_OFF; }
    int lane = f & 63;
    int tile = f >> 6;
    int nt = tile % NT, kt = tile / NT;
    int n  = nt * 16 + (lane & 15);
    int k0 = kt * 32 + ((lane >> 4) & 3) * 8;
    short v[8];
    #pragma unroll
    for (int j = 0; j < 8; ++j) {
        int k = k0 + j;
        float x = (k < KREAL && n < NROW) ? W[k * NROW + n] : 0.0f;
        v[j] = f2bf(x);
    }
    *(short8*)(P + pbase + (long)f * 8) = *(short8*)v;
}

// ---------- fused MLP via MFMA: 64 rows/block (32 points x 2 variants) ----------
#define HSTR 264   // bf16 row stride: 528 B -> row-lanes spread over 8 disjoint bank-quads

__global__ __launch_bounds__(256) void nilut_mfma_kernel(
    const float* __restrict__ param, const short* __restrict__ P,
    const float* __restrict__ b0, const float* __restrict__ b1,
    const float* __restrict__ b2, const float* __restrict__ b3,
    const float* __restrict__ b4, float* __restrict__ lut4,
    unsigned* __restrict__ rng)
{
    __shared__ short Hs[64][HSTR];   // hidden activations, bf16
    __shared__ short Is[64][40];     // layer-0 input rows (K padded to 32)
    __shared__ float OB[64][4];      // layer-4 outputs

    const int t = threadIdx.x;
    const int pblock = blockIdx.x * 32;
    const int lane = t & 63;
    const int wid  = t >> 6;        // 0..3
    const int lr = lane & 15;
    const int hi = lane >> 4;       // 0..3
    const int k8 = hi * 8;

    if (t < 64) {
        int pn = pblock + (t >> 1);
        if (pn >= NPTS) pn = NPTS - 1;
        int v = t & 1;
        int ii = pn / 1089;
        int rem = pn - ii * 1089;
        int jj = rem / 33;
        int kk = rem - jj * 33;
        float r = kk * (1.0f / 32.0f);
        float g = jj * (1.0f / 32.0f);
        float b = ii * (1.0f / 32.0f);
        float lo = fminf(r, fminf(g, b));
        float hv = fmaxf(r, fmaxf(g, b));
        float mid = r + g + b - lo - hv;    // exact: multiples of 1/32
        Is[t][0] = f2bf(r); Is[t][1] = f2bf(g); Is[t][2] = f2bf(b);
        #pragma unroll
        for (int q = 0; q < 5; ++q)
            Is[t][3 + q] = (v == 0) ? f2bf(param[q]) : (short)0;
        Is[t][8] = f2bf(lo); Is[t][9] = f2bf(mid); Is[t][10] = f2bf(hv);
        #pragma unroll
        for (int q = 11; q < 40; ++q) Is[t][q] = (short)0;
    }
    __syncthreads();

    f32x4 acc[4][4];

    // ---- layer 0: (K=32 padded) -> 256, relu ----
    {
        #pragma unroll
        for (int c = 0; c < 4; ++c) {
            float bv = b0[wid * 64 + c * 16 + lr];
            f32x4 in = {bv, bv, bv, bv};
            #pragma unroll
            for (int rt = 0; rt < 4; ++rt) acc[rt][c] = in;
        }
        short8 a[4], bfr[4];
        #pragma unroll
        for (int rt = 0; rt < 4; ++rt) a[rt] = *(const short8*)&Is[rt * 16 + lr][k8];
        #pragma unroll
        for (int c = 0; c < 4; ++c)
            bfr[c] = *(const short8*)(P + ((long)(wid * 4 + c) * 64 + lane) * 8);
        #pragma unroll
        for (int rt = 0; rt < 4; ++rt)
            #pragma unroll
            for (int c = 0; c < 4; ++c)
                acc[rt][c] = __builtin_amdgcn_mfma_f32_16x16x32_bf16(a[rt], bfr[c], acc[rt][c], 0, 0, 0);
        #pragma unroll
        for (int rt = 0; rt < 4; ++rt)
            #pragma unroll
            for (int c = 0; c < 4; ++c)
                #pragma unroll
                for (int q = 0; q < 4; ++q)
                    Hs[rt * 16 + hi * 4 + q][wid * 64 + c * 16 + lr] = f2bf(fmaxf(acc[rt][c][q], 0.0f));
    }
    __syncthreads();

    // ---- layers 1..3: 256 -> 256, tanh ----
    const long loff[3] = {W1P_OFF, W2P_OFF, W3P_OFF};
    const float* bptr[3];
    bptr[0] = b1; bptr[1] = b2; bptr[2] = b3;
    for (int L = 0; L < 3; ++L) {
        const short* WL = P + loff[L];
        const float* bb = bptr[L];
        #pragma unroll
        for (int c = 0; c < 4; ++c) {
            float bv = bb[wid * 64 + c * 16 + lr];
            f32x4 in = {bv, bv, bv, bv};
            #pragma unroll
            for (int rt = 0; rt < 4; ++rt) acc[rt][c] = in;
        }
        #pragma unroll
        for (int kt = 0; kt < 8; ++kt) {
            short8 a[4], bfr[4];
            #pragma unroll
            for (int rt = 0; rt < 4; ++rt)
                a[rt] = *(const short8*)&Hs[rt * 16 + lr][kt * 32 + k8];
            #pragma unroll
            for (int c = 0; c < 4; ++c)
                bfr[c] = *(const short8*)(WL + ((long)(kt * 16 + wid * 4 + c) * 64 + lane) * 8);
            #pragma unroll
            for (int rt = 0; rt < 4; ++rt)
                #pragma unroll
                for (int c = 0; c < 4; ++c)
                    acc[rt][c] = __builtin_amdgcn_mfma_f32_16x16x32_bf16(a[rt], bfr[c], acc[rt][c], 0, 0, 0);
        }
        __syncthreads();
        #pragma unroll
        for (int rt = 0; rt < 4; ++rt)
            #pragma unroll
            for (int c = 0; c < 4; ++c)
                #pragma unroll
                for (int q = 0; q < 4; ++q)
                    Hs[rt * 16 + hi * 4 + q][wid * 64 + c * 16 + lr] = f2bf(fast_tanh(acc[rt][c][q]));
        __syncthreads();
    }

    // ---- layer 4: 256 -> 3 (N padded to 16); wave wid owns row-tile wid ----
    {
        float bv = (lr < 3) ? b4[lr] : 0.0f;
        f32x4 a4 = {bv, bv, bv, bv};
        const short* WL = P + W4P_OFF;
        #pragma unroll
        for (int kt = 0; kt < 8; ++kt) {
            short8 a = *(const short8*)&Hs[wid * 16 + lr][kt * 32 + k8];
            short8 b = *(const short8*)(WL + ((long)kt * 64 + lane) * 8);
            a4 = __builtin_amdgcn_mfma_f32_16x16x32_bf16(a, b, a4, 0, 0, 0);
        }
        if (lr < 3) {
            #pragma unroll
            for (int q = 0; q < 4; ++q)
                OB[wid * 16 + hi * 4 + q][lr] = a4[q];
        }
    }
    __syncthreads();

    // out[n][c] = net(inp) - net(zero_inp) + identity rgb; track global min/max
    // (per-wave atomic tail — replay-validated in round 4)
    float vmn = INFINITY, vmx = -INFINITY;
    if (t < 96) {
        int pl = t / 3, c = t - pl * 3;
        int n = pblock + pl;
        if (n < NPTS) {
            int ii = n / 1089;
            int rem = n - ii * 1089;
            int jj = rem / 33;
            int kk = rem - jj * 33;
            float rgb = (c == 0) ? kk * (1.0f / 32.0f)
                      : (c == 1) ? jj * (1.0f / 32.0f)
                                 : ii * (1.0f / 32.0f);
            float val = OB[2 * pl][c] - OB[2 * pl + 1][c] + rgb;
            lut4[n * 4 + c] = val;
            vmn = val; vmx = val;
        }
    }
    #pragma unroll
    for (int off = 32; off; off >>= 1) {
        vmn = fminf(vmn, __shfl_xor(vmn, off));
        vmx = fmaxf(vmx, __shfl_xor(vmx, off));
    }
    if (lane == 0 && vmn <= vmx) {
        atomicMin(&rng[0], f2ord(vmn));
        atomicMax(&rng[1], f2ord(vmx));
    }
}

// ---------- quantize LUT to packed 11/11/10 codes (one u32 per grid point) ----------
__global__ __launch_bounds__(256) void quantize_lut_kernel(
    const float* __restrict__ lut4, const unsigned* __restrict__ rng,
    unsigned* __restrict__ pcode)
{
    int n = blockIdx.x * 256 + threadIdx.x;
    if (n >= NPTS) return;
    float4 v = *(const float4*)(lut4 + (long)n * 4);
    float mn = ord2f(rng[0]);
    float mx = ord2f(rng[1]);
    float span = fmaxf(mx - mn, 1e-9f);
    float i01 = 2047.0f / span;
    float i2  = 1023.0f / span;
    unsigned c0 = __float2uint_rn(fmaxf(v.x - mn, 0.0f) * i01); c0 = min(c0, 2047u);
    unsigned c1 = __float2uint_rn(fmaxf(v.y - mn, 0.0f) * i01); c1 = min(c1, 2047u);
    unsigned c2 = __float2uint_rn(fmaxf(v.z - mn, 0.0f) * i2);  c2 = min(c2, 1023u);
    pcode[n] = c0 | (c1 << 11) | (c2 << 22);
}

// ---------- trilinear apply: whole packed LUT staged in LDS ----------
// 512 threads/block (8 waves) + 143.7 KB LDS: matches the HW-validated
// AITER shape (512 thr, 160 KB). 1024-thread variant diverged under graph
// replay in round 5 — do not use.
#define LERP(a, b, f) fmaf((f), (b) - (a), (a))
#define CH0(w) ((float)((w) & 2047u))
#define CH1(w) ((float)(((w) >> 11) & 2047u))
#define CH2(w) ((float)((w) >> 22))

#define APPLY_BLOCKS 512
#define APPLY_TPB 512

__global__ __launch_bounds__(512) void apply_lut_kernel(
    const float* __restrict__ img, const unsigned* __restrict__ pcode,
    const unsigned* __restrict__ rng, float* __restrict__ out)
{
    __shared__ __align__(16) unsigned sh[NPTS + 3];

    const int t = threadIdx.x;
    // stage packed LUT: 35937 words = 8984 uint4 + 1 word
    {
        const uint4* src = (const uint4*)pcode;
        uint4* dst = (uint4*)sh;
        for (int i = t; i < 8984; i += APPLY_TPB) dst[i] = src[i];
        if (t == 0) sh[35936] = pcode[35936];
    }
    __syncthreads();

    float mn = ord2f(rng[0]);
    float mx = ord2f(rng[1]);
    float span = fmaxf(mx - mn, 1e-9f);
    float st01 = span * (1.0f / 2047.0f);
    float st2  = span * (1.0f / 1023.0f);

    const int NP = 2160 * 3840;
    const int NQ = NP / 4;                 // 2,073,600 pixel-quads
    const int stride = APPLY_BLOCKS * APPLY_TPB;

    for (int q = blockIdx.x * APPLY_TPB + t; q < NQ; q += stride) {
        int p = q * 4;
        float4 rv = *(const float4*)(img + p);
        float4 gv = *(const float4*)(img + NP + p);
        float4 bv = *(const float4*)(img + 2 * NP + p);

        float rr[4] = {rv.x, rv.y, rv.z, rv.w};
        float gg[4] = {gv.x, gv.y, gv.z, gv.w};
        float bb[4] = {bv.x, bv.y, bv.z, bv.w};
        float ox[4], oy[4], oz[4];

        #pragma unroll
        for (int u = 0; u < 4; ++u) {
            float sr = rr[u] * 32.0f, sg = gg[u] * 32.0f, sb = bb[u] * 32.0f;
            float fir = fminf(fmaxf(floorf(sr), 0.0f), 31.0f);
            float fig = fminf(fmaxf(floorf(sg), 0.0f), 31.0f);
            float fib = fminf(fmaxf(floorf(sb), 0.0f), 31.0f);
            float fr = sr - fir, fg = sg - fig, fb = sb - fib;
            int ir = (int)fir, ig = (int)fig, ib = (int)fib;
            int base = ib * 1089 + ig * 33 + ir;

            unsigned w000 = sh[base],        w001 = sh[base + 1];
            unsigned w010 = sh[base + 33],   w011 = sh[base + 34];
            unsigned w100 = sh[base + 1089], w101 = sh[base + 1090];
            unsigned w110 = sh[base + 1122], w111 = sh[base + 1123];

            float x00 = LERP(CH0(w000), CH0(w001), fr), x01 = LERP(CH0(w010), CH0(w011), fr);
            float x10 = LERP(CH0(w100), CH0(w101), fr), x11 = LERP(CH0(w110), CH0(w111), fr);
            float xc  = LERP(LERP(x00, x01, fg), LERP(x10, x11, fg), fb);
            ox[u] = fmaf(xc, st01, mn);

            float y00 = LERP(CH1(w000), CH1(w001), fr), y01 = LERP(CH1(w010), CH1(w011), fr);
            float y10 = LERP(CH1(w100), CH1(w101), fr), y11 = LERP(CH1(w110), CH1(w111), fr);
            float yc  = LERP(LERP(y00, y01, fg), LERP(y10, y11, fg), fb);
            oy[u] = fmaf(yc, st01, mn);

            float z00 = LERP(CH2(w000), CH2(w001), fr), z01 = LERP(CH2(w010), CH2(w011), fr);
            float z10 = LERP(CH2(w100), CH2(w101), fr), z11 = LERP(CH2(w110), CH2(w111), fr);
            float zc  = LERP(LERP(z00, z01, fg), LERP(z10, z11, fg), fb);
            oz[u] = fmaf(zc, st2, mn);
        }

        *(float4*)(out + p)          = make_float4(ox[0], ox[1], ox[2], ox[3]);
        *(float4*)(out + NP + p)     = make_float4(oy[0], oy[1], oy[2], oy[3]);
        *(float4*)(out + 2 * NP + p) = make_float4(oz[0], oz[1], oz[2], oz[3]);
    }
}

extern "C" void kernel_launch(void* const* d_in, const int* in_sizes, int n_in,
                              void* d_out, int out_size, void* d_ws, size_t ws_size,
                              hipStream_t stream) {
    const float* img   = (const float*)d_in[0];
    const float* param = (const float*)d_in[1];
    const float* W0 = (const float*)d_in[2];
    const float* b0 = (const float*)d_in[3];
    const float* W1 = (const float*)d_in[4];
    const float* b1 = (const float*)d_in[5];
    const float* W2 = (const float*)d_in[6];
    const float* b2 = (const float*)d_in[7];
    const float* W3 = (const float*)d_in[8];
    const float* b3 = (const float*)d_in[9];
    const float* W4 = (const float*)d_in[10];
    const float* b4 = (const float*)d_in[11];

    short*    P     = (short*)d_ws;
    float*    lut4  = (float*)((char*)d_ws + LUT_BYTE_OFF);
    unsigned* rng   = (unsigned*)((char*)d_ws + RNG_BYTE_OFF);
    unsigned* pcode = (unsigned*)((char*)d_ws + PCODE_BYTE_OFF);
    float*    out   = (float*)d_out;

    hipLaunchKernelGGL(pack_weights_kernel, dim3(102), dim3(TPB), 0, stream,
                       W0, W1, W2, W3, W4, P, rng);

    int lut_blocks = (NPTS + 31) / 32;     // 1124
    hipLaunchKernelGGL(nilut_mfma_kernel, dim3(lut_blocks), dim3(TPB), 0, stream,
                       param, P, b0, b1, b2, b3, b4, lut4, rng);

    hipLaunchKernelGGL(quantize_lut_kernel, dim3((NPTS + 255) / 256), dim3(TPB), 0, stream,
                       lut4, rng, pcode);

    hipLaunchKernelGGL(apply_lut_kernel, dim3(APPLY_BLOCKS), dim3(APPLY_TPB), 0, stream,
                       img, pcode, rng, out);
}

// Round 7
// 137.519 us; speedup vs baseline: 1.3081x; 1.3081x over previous
//
#include <hip/hip_runtime.h>
#include <hip/hip_fp16.h>
#include <math.h>

#define NPTS 35937        // 33^3
#define HID 256
#define TPB 256

typedef __attribute__((ext_vector_type(8))) short short8;
typedef __attribute__((ext_vector_type(4))) float f32x4;

// ---------- helpers ----------
__device__ __forceinline__ float fast_tanh(float x) {
    float e = __expf(2.0f * x);
    return 1.0f - __fdividef(2.0f, e + 1.0f);
}

__device__ __forceinline__ short f2bf(float f) {   // RNE float->bf16
    union { float f; unsigned u; } v; v.f = f;
    unsigned r = (v.u + 0x7fffu + ((v.u >> 16) & 1u)) >> 16;
    return (short)r;
}

// HW packed f32x2 -> bf16x2 (RNE), low word = a, high word = b
__device__ __forceinline__ unsigned cvt_pk_bf16(float a, float b) {
    unsigned r;
    asm("v_cvt_pk_bf16_f32 %0, %1, %2" : "=v"(r) : "v"(a), "v"(b));
    return r;
}

// ---------- workspace layout (bytes) ----------
// P      [0, 417792)            bf16 packed weights
// lut4   [417792, 992784)       fp32x4 LUT (35937 * 16 B)
// cells  [992896, 3090048)      fp16x4 duplicated-corner cells: 32^3 * 64 B
#define W1P_OFF 8192
#define W2P_OFF 73728
#define W3P_OFF 139264
#define W4P_OFF 204800
#define LUT_BYTE_OFF 417792
#define CELL_BYTE_OFF 992896

__global__ __launch_bounds__(256) void pack_weights_kernel(
    const float* __restrict__ W0, const float* __restrict__ W1,
    const float* __restrict__ W2, const float* __restrict__ W3,
    const float* __restrict__ W4, short* __restrict__ P)
{
    int id = blockIdx.x * 256 + threadIdx.x;
    if (id >= 26112) return;
    const float* W; int f, NT, KREAL, NROW; long pbase;
    if (id < 1024)       { W = W0; f = id;         NT = 16; KREAL = 11;  NROW = 256; pbase = 0; }
    else if (id < 9216)  { W = W1; f = id - 1024;  NT = 16; KREAL = 256; NROW = 256; pbase = W1P_OFF; }
    else if (id < 17408) { W = W2; f = id - 9216;  NT = 16; KREAL = 256; NROW = 256; pbase = W2P_OFF; }
    else if (id < 25600) { W = W3; f = id - 17408; NT = 16; KREAL = 256; NROW = 256; pbase = W3P_OFF; }
    else                 { W = W4; f = id - 25600; NT = 1;  KREAL = 256; NROW = 3;   pbase = W4P_OFF; }
    int lane = f & 63;
    int tile = f >> 6;
    int nt = tile % NT, kt = tile / NT;
    int n  = nt * 16 + (lane & 15);
    int k0 = kt * 32 + ((lane >> 4) & 3) * 8;
    short v[8];
    #pragma unroll
    for (int j = 0; j < 8; ++j) {
        int k = k0 + j;
        float x = (k < KREAL && n < NROW) ? W[k * NROW + n] : 0.0f;
        v[j] = f2bf(x);
    }
    *(short8*)(P + pbase + (long)f * 8) = *(short8*)v;
}

// ---------- fused MLP via MFMA: 64 rows/block (32 points x 2 variants) ----------
// Layers 0-3 use SWAPPED mfma operands: mfma(W_frag, H_frag) = (H W)^T.
// Per-lane register contents are identical either way (A-frag[i][k] with
// i=lane&15 holds the same data as B-frag[k][j] with j=lane&15), so the
// packed weights and the Hs[row][neuron] layout are unchanged; only the
// D mapping transposes: thread now owns 4 CONSECUTIVE NEURONS at one row
// -> epilogue = 4 tanh + 2 v_cvt_pk_bf16_f32 + 1 ds_write_b64
// (was 64 ds_write_b16 + scalar f2bf bit-twiddling per thread per layer).
#define HSTR 264   // bf16 row stride: 528 B, 16B-aligned rows

__global__ __launch_bounds__(256) void nilut_mfma_kernel(
    const float* __restrict__ param, const short* __restrict__ P,
    const float* __restrict__ b0, const float* __restrict__ b1,
    const float* __restrict__ b2, const float* __restrict__ b3,
    const float* __restrict__ b4, float* __restrict__ lut4)
{
    __shared__ short Hs[64][HSTR];   // hidden activations, bf16 [row][neuron]
    __shared__ short Is[64][40];     // layer-0 input rows (K padded to 32)
    __shared__ float OB[64][4];      // layer-4 outputs

    const int t = threadIdx.x;
    const int pblock = blockIdx.x * 32;
    const int lane = t & 63;
    const int wid  = t >> 6;        // 0..3
    const int lr = lane & 15;
    const int hi = lane >> 4;       // 0..3
    const int k8 = hi * 8;

    if (t < 64) {
        int pn = pblock + (t >> 1);
        if (pn >= NPTS) pn = NPTS - 1;
        int v = t & 1;
        int ii = pn / 1089;
        int rem = pn - ii * 1089;
        int jj = rem / 33;
        int kk = rem - jj * 33;
        float r = kk * (1.0f / 32.0f);
        float g = jj * (1.0f / 32.0f);
        float b = ii * (1.0f / 32.0f);
        float lo = fminf(r, fminf(g, b));
        float hv = fmaxf(r, fmaxf(g, b));
        float mid = r + g + b - lo - hv;    // exact: multiples of 1/32
        Is[t][0] = f2bf(r); Is[t][1] = f2bf(g); Is[t][2] = f2bf(b);
        #pragma unroll
        for (int q = 0; q < 5; ++q)
            Is[t][3 + q] = (v == 0) ? f2bf(param[q]) : (short)0;
        Is[t][8] = f2bf(lo); Is[t][9] = f2bf(mid); Is[t][10] = f2bf(hv);
        #pragma unroll
        for (int q = 11; q < 40; ++q) Is[t][q] = (short)0;
    }
    __syncthreads();

    f32x4 acc[4][4];
    const int nbase = wid * 64 + hi * 4;   // first neuron this thread owns (per c: +c*16)

    // ---- layer 0: (K=32 padded) -> 256, relu ----
    {
        #pragma unroll
        for (int c = 0; c < 4; ++c) {
            float4 bv = *(const float4*)(b0 + nbase + c * 16);
            f32x4 in = {bv.x, bv.y, bv.z, bv.w};
            #pragma unroll
            for (int rt = 0; rt < 4; ++rt) acc[rt][c] = in;
        }
        short8 a[4], bfr[4];
        #pragma unroll
        for (int rt = 0; rt < 4; ++rt) a[rt] = *(const short8*)&Is[rt * 16 + lr][k8];
        #pragma unroll
        for (int c = 0; c < 4; ++c)
            bfr[c] = *(const short8*)(P + ((long)(wid * 4 + c) * 64 + lane) * 8);
        #pragma unroll
        for (int rt = 0; rt < 4; ++rt)
            #pragma unroll
            for (int c = 0; c < 4; ++c)
                acc[rt][c] = __builtin_amdgcn_mfma_f32_16x16x32_bf16(bfr[c], a[rt], acc[rt][c], 0, 0, 0);
        #pragma unroll
        for (int rt = 0; rt < 4; ++rt)
            #pragma unroll
            for (int c = 0; c < 4; ++c) {
                uint2 w;
                w.x = cvt_pk_bf16(fmaxf(acc[rt][c][0], 0.0f), fmaxf(acc[rt][c][1], 0.0f));
                w.y = cvt_pk_bf16(fmaxf(acc[rt][c][2], 0.0f), fmaxf(acc[rt][c][3], 0.0f));
                *(uint2*)&Hs[rt * 16 + lr][nbase + c * 16] = w;
            }
    }
    __syncthreads();

    // ---- layers 1..3: 256 -> 256, tanh ----
    const long loff[3] = {W1P_OFF, W2P_OFF, W3P_OFF};
    const float* bptr[3];
    bptr[0] = b1; bptr[1] = b2; bptr[2] = b3;
    for (int L = 0; L < 3; ++L) {
        const short* WL = P + loff[L];
        const float* bb = bptr[L];
        #pragma unroll
        for (int c = 0; c < 4; ++c) {
            float4 bv = *(const float4*)(bb + nbase + c * 16);
            f32x4 in = {bv.x, bv.y, bv.z, bv.w};
            #pragma unroll
            for (int rt = 0; rt < 4; ++rt) acc[rt][c] = in;
        }
        #pragma unroll
        for (int kt = 0; kt < 8; ++kt) {
            short8 a[4], bfr[4];
            #pragma unroll
            for (int rt = 0; rt < 4; ++rt)
                a[rt] = *(const short8*)&Hs[rt * 16 + lr][kt * 32 + k8];
            #pragma unroll
            for (int c = 0; c < 4; ++c)
                bfr[c] = *(const short8*)(WL + ((long)(kt * 16 + wid * 4 + c) * 64 + lane) * 8);
            #pragma unroll
            for (int rt = 0; rt < 4; ++rt)
                #pragma unroll
                for (int c = 0; c < 4; ++c)
                    acc[rt][c] = __builtin_amdgcn_mfma_f32_16x16x32_bf16(bfr[c], a[rt], acc[rt][c], 0, 0, 0);
        }
        __syncthreads();   // all reads of Hs done before overwrite
        #pragma unroll
        for (int rt = 0; rt < 4; ++rt)
            #pragma unroll
            for (int c = 0; c < 4; ++c) {
                uint2 w;
                w.x = cvt_pk_bf16(fast_tanh(acc[rt][c][0]), fast_tanh(acc[rt][c][1]));
                w.y = cvt_pk_bf16(fast_tanh(acc[rt][c][2]), fast_tanh(acc[rt][c][3]));
                *(uint2*)&Hs[rt * 16 + lr][nbase + c * 16] = w;
            }
        __syncthreads();
    }

    // ---- layer 4: 256 -> 3 (N padded to 16); original operand order ----
    {
        float bv = (lr < 3) ? b4[lr] : 0.0f;
        f32x4 a4 = {bv, bv, bv, bv};
        const short* WL = P + W4P_OFF;
        #pragma unroll
        for (int kt = 0; kt < 8; ++kt) {
            short8 a = *(const short8*)&Hs[wid * 16 + lr][kt * 32 + k8];
            short8 b = *(const short8*)(WL + ((long)kt * 64 + lane) * 8);
            a4 = __builtin_amdgcn_mfma_f32_16x16x32_bf16(a, b, a4, 0, 0, 0);
        }
        if (lr < 3) {
            #pragma unroll
            for (int q = 0; q < 4; ++q)
                OB[wid * 16 + hi * 4 + q][lr] = a4[q];
        }
    }
    __syncthreads();

    // out[n][c] = net(inp) - net(zero_inp) + identity rgb
    if (t < 96) {
        int pl = t / 3, c = t - pl * 3;
        int n = pblock + pl;
        if (n < NPTS) {
            int ii = n / 1089;
            int rem = n - ii * 1089;
            int jj = rem / 33;
            int kk = rem - jj * 33;
            float rgb = (c == 0) ? kk * (1.0f / 32.0f)
                      : (c == 1) ? jj * (1.0f / 32.0f)
                                 : ii * (1.0f / 32.0f);
            lut4[n * 4 + c] = OB[2 * pl][c] - OB[2 * pl + 1][c] + rgb;
        }
    }
}

// ---------- cell expansion: 32^3 cells, 8 corners each, fp16x4 per corner ----------
__global__ __launch_bounds__(256) void expand_cells_kernel(
    const float* __restrict__ lut4, __half* __restrict__ cells)
{
    int id = blockIdx.x * 256 + threadIdx.x;     // cell*8 + corner
    if (id >= 32768 * 8) return;
    int corner = id & 7;
    int cell   = id >> 3;
    int ir = cell & 31, ig = (cell >> 5) & 31, ib = cell >> 10;
    int dr = corner & 1, dg = (corner >> 1) & 1, db = (corner >> 2) & 1;
    int src = (ib + db) * 1089 + (ig + dg) * 33 + (ir + dr);
    float4 v = *(const float4*)(lut4 + (long)src * 4);
    union { __half h[4]; uint2 u; } pk;
    pk.h[0] = __float2half_rn(v.x);
    pk.h[1] = __float2half_rn(v.y);
    pk.h[2] = __float2half_rn(v.z);
    pk.h[3] = __float2half_rn(0.0f);
    *(uint2*)(cells + (long)cell * 32 + corner * 4) = pk.u;
}

// ---------- trilinear apply from duplicated cells ----------
#define LERP(a, b, f) fmaf((f), (b) - (a), (a))

__global__ __launch_bounds__(256) void apply_lut_kernel(
    const float* __restrict__ img, const __half* __restrict__ cells,
    float* __restrict__ out)
{
    const int NP = 2160 * 3840;
    int idx = blockIdx.x * blockDim.x + threadIdx.x;
    int p = idx * 4;
    if (p >= NP) return;

    float4 rv = *(const float4*)(img + p);
    float4 gv = *(const float4*)(img + NP + p);
    float4 bv = *(const float4*)(img + 2 * NP + p);

    float rr[4] = {rv.x, rv.y, rv.z, rv.w};
    float gg[4] = {gv.x, gv.y, gv.z, gv.w};
    float bb[4] = {bv.x, bv.y, bv.z, bv.w};
    float ox[4], oy[4], oz[4];

    #pragma unroll
    for (int u = 0; u < 4; ++u) {
        float sr = rr[u] * 32.0f, sg = gg[u] * 32.0f, sb = bb[u] * 32.0f;
        float fir = fminf(fmaxf(floorf(sr), 0.0f), 31.0f);
        float fig = fminf(fmaxf(floorf(sg), 0.0f), 31.0f);
        float fib = fminf(fmaxf(floorf(sb), 0.0f), 31.0f);
        float fr = sr - fir, fg = sg - fig, fb = sb - fib;
        int ir = (int)fir, ig = (int)fig, ib = (int)fib;

        const short8* cb = (const short8*)(cells + ((long)(ib * 1024 + ig * 32 + ir)) * 32);
        union { short8 s; __half h[8]; } u0, u1, u2, u3;
        u0.s = cb[0];   // corners (0,0,0),(0,0,1)
        u1.s = cb[1];   // corners (0,1,0),(0,1,1)
        u2.s = cb[2];   // corners (1,0,0),(1,0,1)
        u3.s = cb[3];   // corners (1,1,0),(1,1,1)

        float v00[3], v01[3], v10[3], v11[3];
        #pragma unroll
        for (int c = 0; c < 3; ++c) {
            v00[c] = LERP(__half2float(u0.h[c]), __half2float(u0.h[c + 4]), fr);
            v01[c] = LERP(__half2float(u1.h[c]), __half2float(u1.h[c + 4]), fr);
            v10[c] = LERP(__half2float(u2.h[c]), __half2float(u2.h[c + 4]), fr);
            v11[c] = LERP(__half2float(u3.h[c]), __half2float(u3.h[c + 4]), fr);
        }
        ox[u] = LERP(LERP(v00[0], v01[0], fg), LERP(v10[0], v11[0], fg), fb);
        oy[u] = LERP(LERP(v00[1], v01[1], fg), LERP(v10[1], v11[1], fg), fb);
        oz[u] = LERP(LERP(v00[2], v01[2], fg), LERP(v10[2], v11[2], fg), fb);
    }

    *(float4*)(out + p)          = make_float4(ox[0], ox[1], ox[2], ox[3]);
    *(float4*)(out + NP + p)     = make_float4(oy[0], oy[1], oy[2], oy[3]);
    *(float4*)(out + 2 * NP + p) = make_float4(oz[0], oz[1], oz[2], oz[3]);
}

extern "C" void kernel_launch(void* const* d_in, const int* in_sizes, int n_in,
                              void* d_out, int out_size, void* d_ws, size_t ws_size,
                              hipStream_t stream) {
    const float* img   = (const float*)d_in[0];
    const float* param = (const float*)d_in[1];
    const float* W0 = (const float*)d_in[2];
    const float* b0 = (const float*)d_in[3];
    const float* W1 = (const float*)d_in[4];
    const float* b1 = (const float*)d_in[5];
    const float* W2 = (const float*)d_in[6];
    const float* b2 = (const float*)d_in[7];
    const float* W3 = (const float*)d_in[8];
    const float* b3 = (const float*)d_in[9];
    const float* W4 = (const float*)d_in[10];
    const float* b4 = (const float*)d_in[11];

    short*  P     = (short*)d_ws;
    float*  lut4  = (float*)((char*)d_ws + LUT_BYTE_OFF);
    __half* cells = (__half*)((char*)d_ws + CELL_BYTE_OFF);
    float*  out   = (float*)d_out;

    hipLaunchKernelGGL(pack_weights_kernel, dim3(102), dim3(TPB), 0, stream,
                       W0, W1, W2, W3, W4, P);

    int lut_blocks = (NPTS + 31) / 32;     // 1124
    hipLaunchKernelGGL(nilut_mfma_kernel, dim3(lut_blocks), dim3(TPB), 0, stream,
                       param, P, b0, b1, b2, b3, b4, lut4);

    hipLaunchKernelGGL(expand_cells_kernel, dim3(1024), dim3(TPB), 0, stream,
                       lut4, cells);

    const int NP = 2160 * 3840;
    int apply_blocks = (NP / 4 + TPB - 1) / TPB;   // 8100
    hipLaunchKernelGGL(apply_lut_kernel, dim3(apply_blocks), dim3(TPB), 0, stream,
                       img, cells, out);
}